// Round 1
// baseline (103586.267 us; speedup 1.0000x reference)
//
#include <hip/hip_runtime.h>
#include <math.h>

#define B_  32
#define T_  512
#define D_  1024
#define H_  1024
#define G4_ 4096
#define NB  256
#define NT  512
#define KC  128
#define NCHUNK 8   // D_/KC
#define JB  4

// ---------------- grid barrier (device-scope, generation-based) ----------------
__device__ __forceinline__ void gbar(unsigned* cnt, unsigned* gen) {
    __threadfence();           // make this block's global stores visible device-wide
    __syncthreads();
    if (threadIdx.x == 0) {
        unsigned g = __hip_atomic_load(gen, __ATOMIC_RELAXED, __HIP_MEMORY_SCOPE_AGENT);
        unsigned a = __hip_atomic_fetch_add(cnt, 1u, __ATOMIC_ACQ_REL, __HIP_MEMORY_SCOPE_AGENT);
        if (a == NB - 1u) {
            __hip_atomic_store(cnt, 0u, __ATOMIC_RELAXED, __HIP_MEMORY_SCOPE_AGENT);
            __hip_atomic_store(gen, g + 1u, __ATOMIC_RELEASE, __HIP_MEMORY_SCOPE_AGENT);
        } else {
            while (__hip_atomic_load(gen, __ATOMIC_ACQUIRE, __HIP_MEMORY_SCOPE_AGENT) == g) {
                __builtin_amdgcn_s_sleep(1);
            }
        }
    }
    __syncthreads();
}

__device__ __forceinline__ float hardsig(float z) {
    return fminf(fmaxf(0.2f * z + 0.5f, 0.0f), 1.0f);
}

// ---------------- fused persistent 2-layer LSTM ----------------
__global__ __launch_bounds__(NT, 1)
void lstm_persist(const float* __restrict__ x,
                  const float* __restrict__ W0, const float* __restrict__ U0, const float* __restrict__ b0,
                  const float* __restrict__ W1, const float* __restrict__ U1, const float* __restrict__ b1,
                  float* __restrict__ h1seq,   // [T][B][H]
                  float* __restrict__ h2buf,   // [2][B][H]
                  const float* __restrict__ zbuf, // [B][H] zeros
                  unsigned* __restrict__ bar_cnt, unsigned* __restrict__ bar_gen,
                  float* __restrict__ out)     // [B][H]
{
    __shared__ float Ures[4][H_][4];   // 64 KB resident U slice: [gate][k][jj]
    __shared__ float Wch [4][KC][4];   //  8 KB streamed W chunk
    __shared__ float xs  [KC][36];     // 18 KB staged x_t chunk (transposed, pad 36)
    __shared__ float hs  [KC][36];     // 18 KB staged h_{t-1} chunk
    __shared__ float zfin[4][B_][4];   //  2 KB reduced gate pre-activations

    const int tid = threadIdx.x;
    const int bid = blockIdx.x;
    const int j0  = bid * JB;          // owned h-columns j0..j0+3
    const int kq  = tid & 15;          // K-split id (16-way)
    const int tg  = tid >> 4;          // 0..31
    const int bg  = tg >> 2;           // 0..7: b-group (4 rows) — one per wave
    const int g   = tg & 3;            // gate id

    const int cb = tid >> 2;           // combine-thread batch (tid<128)
    const int cj = tid & 3;            // combine-thread jj

    float creg = 0.f;
    float bias_i = 0.f, bias_f = 0.f, bias_g = 0.f, bias_o = 0.f;

    for (int layer = 0; layer < 2; ++layer) {
        const float* Wl = layer ? W1 : W0;
        const float* Ul = layer ? U1 : U0;
        const float* bl = layer ? b1 : b0;

        // ---- stage resident U slice (once per layer) ----
        __syncthreads();
        #pragma unroll
        for (int r = 0; r < 8; ++r) {
            int idx = r * NT + tid;        // 0..4095
            int kk  = idx >> 2;
            int gg  = idx & 3;
            *(float4*)&Ures[gg][kk][0] =
                *(const float4*)&Ul[(size_t)kk * G4_ + (size_t)gg * H_ + j0];
        }
        if (tid < 128) {
            bias_i = bl[0 * H_ + j0 + cj];
            bias_f = bl[1 * H_ + j0 + cj];
            bias_g = bl[2 * H_ + j0 + cj];
            bias_o = bl[3 * H_ + j0 + cj];
            creg = 0.f;
        }
        __syncthreads();

        for (int t = 0; t < T_; ++t) {
            const float* hprev = (t == 0) ? zbuf
                               : (layer == 0 ? h1seq + (size_t)(t - 1) * B_ * H_
                                             : h2buf + (size_t)((t - 1) & 1) * B_ * H_);
            const float* xin;  size_t xstride;
            if (layer == 0) { xin = x     + (size_t)t * D_;       xstride = (size_t)T_ * D_; }
            else            { xin = h1seq + (size_t)t * B_ * H_;  xstride = (size_t)H_; }

            float acc[4][4];
            #pragma unroll
            for (int m = 0; m < 4; ++m)
                #pragma unroll
                for (int n = 0; n < 4; ++n) acc[m][n] = 0.f;

            for (int c8 = 0; c8 < NCHUNK; ++c8) {
                const int k0 = c8 * KC;
                __syncthreads();  // staging buffers free
                {   // stage xs / hs (transposed) — coalesced 256B-per-16-lane reads
                    int sb = tid >> 4;    // 0..31 batch row
                    int q  = tid & 15;
                    const float* xr = xin + (size_t)sb * xstride + k0;
                    float4 v0 = *(const float4*)&xr[q * 4];
                    float4 v1 = *(const float4*)&xr[64 + q * 4];
                    xs[q*4+0][sb] = v0.x; xs[q*4+1][sb] = v0.y;
                    xs[q*4+2][sb] = v0.z; xs[q*4+3][sb] = v0.w;
                    xs[64+q*4+0][sb] = v1.x; xs[64+q*4+1][sb] = v1.y;
                    xs[64+q*4+2][sb] = v1.z; xs[64+q*4+3][sb] = v1.w;
                    const float* hr = hprev + (size_t)sb * H_ + k0;
                    float4 h0 = *(const float4*)&hr[q * 4];
                    float4 h1 = *(const float4*)&hr[64 + q * 4];
                    hs[q*4+0][sb] = h0.x; hs[q*4+1][sb] = h0.y;
                    hs[q*4+2][sb] = h0.z; hs[q*4+3][sb] = h0.w;
                    hs[64+q*4+0][sb] = h1.x; hs[64+q*4+1][sb] = h1.y;
                    hs[64+q*4+2][sb] = h1.z; hs[64+q*4+3][sb] = h1.w;
                    // stage W chunk
                    int wk = tid >> 2;    // 0..127
                    int wg = tid & 3;
                    *(float4*)&Wch[wg][wk][0] =
                        *(const float4*)&Wl[(size_t)(k0 + wk) * G4_ + (size_t)wg * H_ + j0];
                }
                __syncthreads();
                #pragma unroll
                for (int i = 0; i < KC / 16; ++i) {
                    int kk = i * 16 + kq;
                    float4 xv = *(const float4*)&xs[kk][bg * 4];
                    float4 hv = *(const float4*)&hs[kk][bg * 4];
                    float4 wv = *(const float4*)&Wch[g][kk][0];
                    float4 uv = *(const float4*)&Ures[g][k0 + kk][0];
                    #define FMA4(A, XE, HE) \
                        acc[A][0] += (XE)*wv.x + (HE)*uv.x; \
                        acc[A][1] += (XE)*wv.y + (HE)*uv.y; \
                        acc[A][2] += (XE)*wv.z + (HE)*uv.z; \
                        acc[A][3] += (XE)*wv.w + (HE)*uv.w;
                    FMA4(0, xv.x, hv.x)
                    FMA4(1, xv.y, hv.y)
                    FMA4(2, xv.z, hv.z)
                    FMA4(3, xv.w, hv.w)
                    #undef FMA4
                }
            }

            // ---- reduce the 16-way K-split (consecutive lanes) ----
            #pragma unroll
            for (int m = 0; m < 4; ++m)
                #pragma unroll
                for (int n = 0; n < 4; ++n) {
                    float v = acc[m][n];
                    v += __shfl_xor(v, 1);
                    v += __shfl_xor(v, 2);
                    v += __shfl_xor(v, 4);
                    v += __shfl_xor(v, 8);
                    acc[m][n] = v;
                }
            if (kq == 0) {
                #pragma unroll
                for (int m = 0; m < 4; ++m)
                    #pragma unroll
                    for (int n = 0; n < 4; ++n)
                        zfin[g][bg * 4 + m][n] = acc[m][n];
            }
            __syncthreads();

            // ---- gate combine + state update (128 threads) ----
            if (tid < 128) {
                float zi = zfin[0][cb][cj] + bias_i;
                float zf = zfin[1][cb][cj] + bias_f;
                float zg = zfin[2][cb][cj] + bias_g;
                float zo = zfin[3][cb][cj] + bias_o;
                float ig = hardsig(zi);
                float fg = hardsig(zf);
                float gg = tanhf(zg);
                float og = hardsig(zo);
                creg = fg * creg + ig * gg;
                float hval = og * tanhf(creg);
                if (layer == 0) {
                    h1seq[((size_t)t * B_ + cb) * H_ + j0 + cj] = hval;
                } else {
                    h2buf[(size_t)(t & 1) * B_ * H_ + (size_t)cb * H_ + j0 + cj] = hval;
                    if (t == T_ - 1) out[(size_t)cb * H_ + j0 + cj] = hval;
                }
            }
            gbar(bar_cnt, bar_gen);
        }
    }
}

extern "C" void kernel_launch(void* const* d_in, const int* in_sizes, int n_in,
                              void* d_out, int out_size, void* d_ws, size_t ws_size,
                              hipStream_t stream) {
    const float* x  = (const float*)d_in[0];
    const float* W0 = (const float*)d_in[1];
    const float* U0 = (const float*)d_in[2];
    const float* b0 = (const float*)d_in[3];
    const float* W1 = (const float*)d_in[4];
    const float* U1 = (const float*)d_in[5];
    const float* b1 = (const float*)d_in[6];
    float* out = (float*)d_out;

    char* ws = (char*)d_ws;
    float*    h1seq = (float*)ws;                                  // 64 MiB: [T][B][H]
    float*    h2buf = (float*)(ws + 67108864);                     // 256 KiB: [2][B][H]
    float*    zbuf  = (float*)(ws + 67108864 + 262144);            // 128 KiB zeros
    unsigned* bar   = (unsigned*)(ws + 67108864 + 262144 + 131072);// barrier words

    // zero the zero-buffer + barrier state every launch (graph-capture safe)
    hipMemsetAsync(zbuf, 0, 131072 + 128, stream);

    hipLaunchKernelGGL(lstm_persist, dim3(NB), dim3(NT), 0, stream,
                       x, W0, U0, b0, W1, U1, b1,
                       h1seq, h2buf, zbuf, bar, bar + 16, out);
}

// Round 2
// 60723.590 us; speedup vs baseline: 1.7059x; 1.7059x over previous
//
#include <hip/hip_runtime.h>
#include <hip/hip_bf16.h>
#include <math.h>

#define B_  32
#define T_  512
#define D_  1024
#define H_  1024
#define G4_ 4096
#define NB  256
#define NT  512

typedef __attribute__((ext_vector_type(8))) short short8;
typedef __attribute__((ext_vector_type(4))) float f32x4;

__device__ __forceinline__ float hardsig(float z) {
    return fminf(fmaxf(0.2f * z + 0.5f, 0.0f), 1.0f);
}

// split fp32 into hi+lo bf16 (RTN)
__device__ __forceinline__ void split2(float f, short& hi, short& lo) {
    __hip_bfloat16 h = __float2bfloat16(f);
    float hf = __bfloat162float(h);
    __hip_bfloat16 l = __float2bfloat16(f - hf);
    hi = *(short*)&h;
    lo = *(short*)&l;
}

__global__ __launch_bounds__(NT, 1)
void lstm_mfma(const float* __restrict__ x,
               const float* __restrict__ W0, const float* __restrict__ U0, const float* __restrict__ b0,
               const float* __restrict__ W1, const float* __restrict__ U1, const float* __restrict__ b1,
               unsigned short* __restrict__ h1hi, unsigned short* __restrict__ h1lo,
               unsigned short* __restrict__ h2hi, unsigned short* __restrict__ h2lo,
               const unsigned short* __restrict__ zpage,
               unsigned* __restrict__ leafcnt, unsigned* __restrict__ rootcnt,
               unsigned* __restrict__ gen,
               float* __restrict__ out)
{
    // split-bf16 weights, MFMA-fragment-ordered: [mat][ki*512 + lane*8 + e]
    __shared__ short Wh[2][16384];   // 64 KB
    __shared__ short Wl[2][16384];   // 64 KB
    __shared__ float red[2][4][16][17]; // 8.5 KB partial C tiles [mt][ksplit][row][col+pad]

    const int tid  = threadIdx.x;
    const int bid  = blockIdx.x;
    const int j0   = bid * 4;        // owned h-columns j0..j0+3
    const int w    = tid >> 6;       // wave 0..7
    const int lane = tid & 63;
    const int s    = w >> 1;         // K-slice 0..3 (0,1: x@W; 2,3: h@U)
    const int mt   = w & 1;          // m-tile (batch half)
    const int ln15 = lane & 15;
    const int lhi  = lane >> 4;      // 0..3

    const int cb = tid >> 2;         // combine: batch (tid<128)
    const int cj = tid & 3;          // combine: jj

    float creg = 0.f;
    float bias[4] = {0.f, 0.f, 0.f, 0.f};

    for (int layer = 0; layer < 2; ++layer) {
        const float* Wmat = layer ? W1 : W0;
        const float* Umat = layer ? U1 : U0;
        const float* bl   = layer ? b1 : b0;

        __syncthreads();   // previous layer's last step fully done with LDS
        // ---- convert W,U slices to split-bf16 fragment layout in LDS ----
        for (int m = 0; m < 2; ++m) {
            const float* src = m ? Umat : Wmat;
            for (int fi = tid; fi < 4096; fi += NT) {
                int g = fi & 3, k = fi >> 2;
                float4 v = *(const float4*)&src[(size_t)k * G4_ + (size_t)g * H_ + j0];
                int ki = k >> 5, kf = k & 31;
                int e = kf & 7;
                int flbase = ((kf >> 3) << 4) | (g << 2);
                short hi, lo;
                split2(v.x, hi, lo);
                Wh[m][ki*512 + (flbase+0)*8 + e] = hi; Wl[m][ki*512 + (flbase+0)*8 + e] = lo;
                split2(v.y, hi, lo);
                Wh[m][ki*512 + (flbase+1)*8 + e] = hi; Wl[m][ki*512 + (flbase+1)*8 + e] = lo;
                split2(v.z, hi, lo);
                Wh[m][ki*512 + (flbase+2)*8 + e] = hi; Wl[m][ki*512 + (flbase+2)*8 + e] = lo;
                split2(v.w, hi, lo);
                Wh[m][ki*512 + (flbase+3)*8 + e] = hi; Wl[m][ki*512 + (flbase+3)*8 + e] = lo;
            }
        }
        if (tid < 128) {
            #pragma unroll
            for (int g = 0; g < 4; ++g) bias[g] = bl[(size_t)g * H_ + j0 + cj];
            creg = 0.f;
        }
        __syncthreads();

        for (int t = 0; t < T_; ++t) {
            const int q = layer * T_ + t;     // global step index
            f32x4 acc = {0.f, 0.f, 0.f, 0.f};
            const int b = mt * 16 + ln15;     // A-row (batch) this lane loads

            if (s < 2) {
                // ---------- x-phase: A = x-source, B = W. Never waits. ----------
                if (layer == 0) {
                    const float* xr = x + ((size_t)b * T_ + t) * D_;
                    #pragma unroll 4
                    for (int ki = 0; ki < 16; ++ki) {
                        int d = s * 512 + ki * 32 + lhi * 8;
                        float4 v0 = *(const float4*)&xr[d];
                        float4 v1 = *(const float4*)&xr[d + 4];
                        short8 ah, al; short hi, lo;
                        split2(v0.x, hi, lo); ah[0]=hi; al[0]=lo;
                        split2(v0.y, hi, lo); ah[1]=hi; al[1]=lo;
                        split2(v0.z, hi, lo); ah[2]=hi; al[2]=lo;
                        split2(v0.w, hi, lo); ah[3]=hi; al[3]=lo;
                        split2(v1.x, hi, lo); ah[4]=hi; al[4]=lo;
                        split2(v1.y, hi, lo); ah[5]=hi; al[5]=lo;
                        split2(v1.z, hi, lo); ah[6]=hi; al[6]=lo;
                        split2(v1.w, hi, lo); ah[7]=hi; al[7]=lo;
                        int kiG = s * 16 + ki;
                        short8 wh = *(const short8*)&Wh[0][kiG * 512 + lane * 8];
                        short8 wl = *(const short8*)&Wl[0][kiG * 512 + lane * 8];
                        acc = __builtin_amdgcn_mfma_f32_16x16x32_bf16(ah, wh, acc, 0, 0, 0);
                        acc = __builtin_amdgcn_mfma_f32_16x16x32_bf16(al, wh, acc, 0, 0, 0);
                        acc = __builtin_amdgcn_mfma_f32_16x16x32_bf16(ah, wl, acc, 0, 0, 0);
                    }
                } else {
                    const unsigned short* xh = h1hi + ((size_t)t * B_ + b) * H_;
                    const unsigned short* xl = h1lo + ((size_t)t * B_ + b) * H_;
                    #pragma unroll 4
                    for (int ki = 0; ki < 16; ++ki) {
                        int d = s * 512 + ki * 32 + lhi * 8;
                        short8 ah = *(const short8*)&xh[d];
                        short8 al = *(const short8*)&xl[d];
                        int kiG = s * 16 + ki;
                        short8 wh = *(const short8*)&Wh[0][kiG * 512 + lane * 8];
                        short8 wl = *(const short8*)&Wl[0][kiG * 512 + lane * 8];
                        acc = __builtin_amdgcn_mfma_f32_16x16x32_bf16(ah, wh, acc, 0, 0, 0);
                        acc = __builtin_amdgcn_mfma_f32_16x16x32_bf16(al, wh, acc, 0, 0, 0);
                        acc = __builtin_amdgcn_mfma_f32_16x16x32_bf16(ah, wl, acc, 0, 0, 0);
                    }
                }
            } else {
                // ---------- h-phase: wait for all blocks to finish step q-1 ----------
                if (__hip_atomic_load(gen, __ATOMIC_RELAXED, __HIP_MEMORY_SCOPE_AGENT) < (unsigned)q) {
                    while (__hip_atomic_load(gen, __ATOMIC_RELAXED, __HIP_MEMORY_SCOPE_AGENT) < (unsigned)q)
                        __builtin_amdgcn_s_sleep(2);
                }
                __builtin_amdgcn_fence(__ATOMIC_ACQUIRE, "agent");

                const unsigned short *hh, *hl;
                if (t == 0)          { hh = zpage; hl = zpage; }
                else if (layer == 0) { hh = h1hi + ((size_t)(t-1) * B_ + b) * H_;
                                       hl = h1lo + ((size_t)(t-1) * B_ + b) * H_; }
                else                 { hh = h2hi + ((size_t)((t-1)&1) * B_ + b) * H_;
                                       hl = h2lo + ((size_t)((t-1)&1) * B_ + b) * H_; }
                const int sk = (s - 2) * 512;
                #pragma unroll 4
                for (int ki = 0; ki < 16; ++ki) {
                    int d = sk + ki * 32 + lhi * 8;
                    short8 ah = *(const short8*)&hh[d];
                    short8 al = *(const short8*)&hl[d];
                    int kiG = (s - 2) * 16 + ki;
                    short8 uh = *(const short8*)&Wh[1][kiG * 512 + lane * 8];
                    short8 ul = *(const short8*)&Wl[1][kiG * 512 + lane * 8];
                    acc = __builtin_amdgcn_mfma_f32_16x16x32_bf16(ah, uh, acc, 0, 0, 0);
                    acc = __builtin_amdgcn_mfma_f32_16x16x32_bf16(al, uh, acc, 0, 0, 0);
                    acc = __builtin_amdgcn_mfma_f32_16x16x32_bf16(ah, ul, acc, 0, 0, 0);
                }
            }

            // ---- publish partial C tiles ----
            #pragma unroll
            for (int i = 0; i < 4; ++i)
                red[mt][s][lhi * 4 + i][ln15] = acc[i];
            __syncthreads();

            // ---- gate combine + state update (128 threads: b=cb, col=j0+cj) ----
            if (tid < 128) {
                const int rmt = cb >> 4, rr = cb & 15;
                float z[4];
                #pragma unroll
                for (int g = 0; g < 4; ++g) {
                    int n = g * 4 + cj;
                    z[g] = red[rmt][0][rr][n] + red[rmt][1][rr][n]
                         + red[rmt][2][rr][n] + red[rmt][3][rr][n] + bias[g];
                }
                float ig = hardsig(z[0]);
                float fg = hardsig(z[1]);
                float gg = tanhf(z[2]);
                float og = hardsig(z[3]);
                creg = fg * creg + ig * gg;
                float hval = og * tanhf(creg);
                short hi, lo; split2(hval, hi, lo);
                size_t oidx = (size_t)cb * H_ + j0 + cj;
                if (layer == 0) {
                    h1hi[(size_t)t * B_ * H_ + oidx] = (unsigned short)hi;
                    h1lo[(size_t)t * B_ * H_ + oidx] = (unsigned short)lo;
                } else {
                    h2hi[(size_t)(t & 1) * B_ * H_ + oidx] = (unsigned short)hi;
                    h2lo[(size_t)(t & 1) * B_ * H_ + oidx] = (unsigned short)lo;
                    if (t == T_ - 1) out[oidx] = hval;
                }
            }

            __threadfence();      // agent-release of h writes (L2 writeback)
            __syncthreads();

            // ---- tree arrive (monotonic counters; release chain to gen) ----
            if (tid == 0) {
                unsigned a = __hip_atomic_fetch_add(&leafcnt[(bid >> 4) * 16], 1u,
                                                    __ATOMIC_ACQ_REL, __HIP_MEMORY_SCOPE_AGENT);
                if ((a & 15u) == 15u) {
                    unsigned r = __hip_atomic_fetch_add(rootcnt, 1u,
                                                        __ATOMIC_ACQ_REL, __HIP_MEMORY_SCOPE_AGENT);
                    if ((r & 15u) == 15u) {
                        __hip_atomic_store(gen, (unsigned)(q + 1),
                                           __ATOMIC_RELEASE, __HIP_MEMORY_SCOPE_AGENT);
                    }
                }
            }
        }
    }
}

extern "C" void kernel_launch(void* const* d_in, const int* in_sizes, int n_in,
                              void* d_out, int out_size, void* d_ws, size_t ws_size,
                              hipStream_t stream) {
    const float* x  = (const float*)d_in[0];
    const float* W0 = (const float*)d_in[1];
    const float* U0 = (const float*)d_in[2];
    const float* b0 = (const float*)d_in[3];
    const float* W1 = (const float*)d_in[4];
    const float* U1 = (const float*)d_in[5];
    const float* b1 = (const float*)d_in[6];
    float* out = (float*)d_out;

    char* ws = (char*)d_ws;
    const size_t off_h1hi = 0;                       // 32 MiB [T][B][H] bf16
    const size_t off_h1lo = 33554432;                // 32 MiB
    const size_t off_h2hi = 67108864;                // 128 KiB [2][B][H] bf16
    const size_t off_h2lo = 67239936;                // 128 KiB
    const size_t off_zp   = 67371008;                // 4 KiB zero page
    const size_t off_bar  = 67375104;                // 4 KiB barrier state

    unsigned short* h1hi = (unsigned short*)(ws + off_h1hi);
    unsigned short* h1lo = (unsigned short*)(ws + off_h1lo);
    unsigned short* h2hi = (unsigned short*)(ws + off_h2hi);
    unsigned short* h2lo = (unsigned short*)(ws + off_h2lo);
    unsigned short* zp   = (unsigned short*)(ws + off_zp);
    unsigned* bar        = (unsigned*)(ws + off_bar);  // leafcnt[16*16], root@+1024B, gen@+1088B

    // reset zero page + all barrier counters every launch (graph-capture safe)
    hipMemsetAsync(ws + off_zp, 0, 8192, stream);

    hipLaunchKernelGGL(lstm_mfma, dim3(NB), dim3(NT), 0, stream,
                       x, W0, U0, b0, W1, U1, b1,
                       h1hi, h1lo, h2hi, h2lo, zp,
                       bar, bar + 256, bar + 272, out);
}

// Round 3
// 10530.567 us; speedup vs baseline: 9.8367x; 5.7664x over previous
//
#include <hip/hip_runtime.h>
#include <hip/hip_bf16.h>
#include <math.h>

#define B_  32
#define T_  512
#define D_  1024
#define H_  1024
#define G4_ 4096
#define NB  256
#define NT  512

typedef __attribute__((ext_vector_type(8))) short short8;
typedef __attribute__((ext_vector_type(4))) float f32x4;

__device__ __forceinline__ float hardsig(float z) {
    return fminf(fmaxf(0.2f * z + 0.5f, 0.0f), 1.0f);
}
// split fp32 into hi+lo bf16 (RTN)
__device__ __forceinline__ void split2(float f, short& hi, short& lo) {
    __hip_bfloat16 h = __float2bfloat16(f);
    float hf = __bfloat162float(h);
    __hip_bfloat16 l = __float2bfloat16(f - hf);
    hi = *(short*)&h; lo = *(short*)&l;
}
__device__ __forceinline__ void unpack8(const unsigned p[8], short8& ah, short8& al) {
    #pragma unroll
    for (int e = 0; e < 8; ++e) {
        ah[e] = (short)(p[e] >> 16);
        al[e] = (short)(p[e] & 0xffffu);
    }
}

__global__ __launch_bounds__(NT, 1)
void lstm_mfma2(const float* __restrict__ x,
                const float* __restrict__ W0, const float* __restrict__ U0, const float* __restrict__ b0,
                const float* __restrict__ W1, const float* __restrict__ U1, const float* __restrict__ b1,
                unsigned* __restrict__ h1pk,        // [T][B][H] packed (hi<<16)|lo
                unsigned* __restrict__ h2pk,        // [2][B][H] packed
                const unsigned* __restrict__ zpage, // [B][H] zeros
                unsigned* __restrict__ bar,         // leaf[i*16] i<16, root@[256], genrep@[272+i*16]
                float* __restrict__ out)            // [B][H]
{
    __shared__ short Wh[2][16384];        // 64 KB  hi-bf16 weights (frag order)
    __shared__ short Wl[2][16384];        // 64 KB  lo-bf16 weights
    __shared__ float red[2][2][4][16][17];// 17 KB  partial C tiles [par][mt][s][row][col+pad]

    const int tid  = threadIdx.x;
    const int bid  = blockIdx.x;
    const int j0   = bid * 4;            // owned h-columns
    const int w    = tid >> 6;
    const int lane = tid & 63;
    const int s    = w >> 1;             // 0,1: x@W waves; 2,3: h@U waves
    const int mt   = w & 1;              // batch half
    const int ln15 = lane & 15;
    const int lhi  = lane >> 4;
    const int b    = mt * 16 + ln15;     // A-row (batch) this lane loads

    const int cb = tid >> 2;             // combine: batch row (tid<128)
    const int cj = tid & 3;              // combine: owned-col idx

    unsigned* leafp = &bar[(bid >> 4) * 16];
    unsigned* rootp = &bar[256];
    unsigned* genp  = &bar[272 + (bid >> 4) * 16];

    float creg = 0.f;
    float bias[4] = {0.f, 0.f, 0.f, 0.f};

    #pragma unroll
    for (int layer = 0; layer < 2; ++layer) {
        const float* Wmat = layer ? W1 : W0;
        const float* Umat = layer ? U1 : U0;
        const float* bl   = layer ? b1 : b0;

        __syncthreads();  // all waves done with previous layer's LDS
        // ---- convert W,U 16-col slices to split-bf16 fragment layout ----
        for (int m = 0; m < 2; ++m) {
            const float* src = m ? Umat : Wmat;
            for (int fi = tid; fi < 4096; fi += NT) {
                int g = fi & 3, k = fi >> 2;
                float4 v = *(const float4*)&src[(size_t)k * G4_ + (size_t)g * H_ + j0];
                int ki = k >> 5, kf = k & 31;
                int e = kf & 7;
                int flbase = ((kf >> 3) << 4) | (g << 2);
                short hi, lo;
                split2(v.x, hi, lo); Wh[m][ki*512+(flbase+0)*8+e]=hi; Wl[m][ki*512+(flbase+0)*8+e]=lo;
                split2(v.y, hi, lo); Wh[m][ki*512+(flbase+1)*8+e]=hi; Wl[m][ki*512+(flbase+1)*8+e]=lo;
                split2(v.z, hi, lo); Wh[m][ki*512+(flbase+2)*8+e]=hi; Wl[m][ki*512+(flbase+2)*8+e]=lo;
                split2(v.w, hi, lo); Wh[m][ki*512+(flbase+3)*8+e]=hi; Wl[m][ki*512+(flbase+3)*8+e]=lo;
            }
        }
        if (tid < 128) {
            #pragma unroll
            for (int g = 0; g < 4; ++g) bias[g] = bl[(size_t)g * H_ + j0 + cj];
            creg = 0.f;
        }
        __syncthreads();

        for (int t = 0; t < T_; ++t) {
            const int q   = layer * T_ + t;
            const int par = q & 1;
            f32x4 a0 = {0,0,0,0}, a1 = {0,0,0,0}, a2 = {0,0,0,0};

            if (s < 2) {
                // ---------------- x-phase (never waits) ----------------
                if (layer == 0) {
                    const float* xr = x + ((size_t)b * T_ + t) * D_;
                    #pragma unroll 4
                    for (int ki = 0; ki < 16; ++ki) {
                        const int d = s * 512 + ki * 32 + lhi * 8;
                        float4 v0 = *(const float4*)&xr[d];
                        float4 v1 = *(const float4*)&xr[d + 4];
                        short8 ah, al; short hi, lo;
                        split2(v0.x,hi,lo); ah[0]=hi; al[0]=lo;
                        split2(v0.y,hi,lo); ah[1]=hi; al[1]=lo;
                        split2(v0.z,hi,lo); ah[2]=hi; al[2]=lo;
                        split2(v0.w,hi,lo); ah[3]=hi; al[3]=lo;
                        split2(v1.x,hi,lo); ah[4]=hi; al[4]=lo;
                        split2(v1.y,hi,lo); ah[5]=hi; al[5]=lo;
                        split2(v1.z,hi,lo); ah[6]=hi; al[6]=lo;
                        split2(v1.w,hi,lo); ah[7]=hi; al[7]=lo;
                        const int kiG = s * 16 + ki;
                        short8 wh = *(const short8*)&Wh[0][kiG*512 + lane*8];
                        short8 wl = *(const short8*)&Wl[0][kiG*512 + lane*8];
                        a0 = __builtin_amdgcn_mfma_f32_16x16x32_bf16(ah, wh, a0, 0, 0, 0);
                        a1 = __builtin_amdgcn_mfma_f32_16x16x32_bf16(al, wh, a1, 0, 0, 0);
                        a2 = __builtin_amdgcn_mfma_f32_16x16x32_bf16(ah, wl, a2, 0, 0, 0);
                    }
                } else {
                    const unsigned* hp = h1pk + ((size_t)t * B_ + b) * H_;
                    #pragma unroll 4
                    for (int ki = 0; ki < 16; ++ki) {
                        const int d = s * 512 + ki * 32 + lhi * 8;
                        uint4 v0 = *(const uint4*)&hp[d];
                        uint4 v1 = *(const uint4*)&hp[d + 4];
                        unsigned p[8] = {v0.x,v0.y,v0.z,v0.w,v1.x,v1.y,v1.z,v1.w};
                        short8 ah, al; unpack8(p, ah, al);
                        const int kiG = s * 16 + ki;
                        short8 wh = *(const short8*)&Wh[0][kiG*512 + lane*8];
                        short8 wl = *(const short8*)&Wl[0][kiG*512 + lane*8];
                        a0 = __builtin_amdgcn_mfma_f32_16x16x32_bf16(ah, wh, a0, 0, 0, 0);
                        a1 = __builtin_amdgcn_mfma_f32_16x16x32_bf16(al, wh, a1, 0, 0, 0);
                        a2 = __builtin_amdgcn_mfma_f32_16x16x32_bf16(ah, wl, a2, 0, 0, 0);
                    }
                }
            } else {
                // ---------------- h-phase: wait for step q-1 globally done ----------------
                if (lane == 0) {
                    while (__hip_atomic_load(genp, __ATOMIC_RELAXED, __HIP_MEMORY_SCOPE_AGENT) < (unsigned)q)
                        __builtin_amdgcn_s_sleep(4);
                }
                asm volatile("" ::: "memory");   // no load hoisting above the poll
                const int sk = (s - 2) * 512;
                if (layer == 0) {
                    // unique addresses per t -> plain cached loads are safe (first touch after LLC publish)
                    const unsigned* hp = (t == 0) ? (zpage + (size_t)b * H_)
                                                  : (h1pk + ((size_t)(t-1) * B_ + b) * H_);
                    #pragma unroll 4
                    for (int ki = 0; ki < 16; ++ki) {
                        const int d = sk + ki * 32 + lhi * 8;
                        uint4 v0 = *(const uint4*)&hp[d];
                        uint4 v1 = *(const uint4*)&hp[d + 4];
                        unsigned p[8] = {v0.x,v0.y,v0.z,v0.w,v1.x,v1.y,v1.z,v1.w};
                        short8 ah, al; unpack8(p, ah, al);
                        const int kiG = (s - 2) * 16 + ki;
                        short8 uh = *(const short8*)&Wh[1][kiG*512 + lane*8];
                        short8 ul = *(const short8*)&Wl[1][kiG*512 + lane*8];
                        a0 = __builtin_amdgcn_mfma_f32_16x16x32_bf16(ah, uh, a0, 0, 0, 0);
                        a1 = __builtin_amdgcn_mfma_f32_16x16x32_bf16(al, uh, a1, 0, 0, 0);
                        a2 = __builtin_amdgcn_mfma_f32_16x16x32_bf16(ah, ul, a2, 0, 0, 0);
                    }
                } else {
                    // h2 double-buffer reuses addresses -> bypass caches with agent-scope loads
                    const unsigned long long* hp64 = (const unsigned long long*)
                        ((t == 0) ? (zpage + (size_t)b * H_)
                                  : (h2pk + (size_t)((t-1)&1) * B_ * H_ + (size_t)b * H_));
                    #pragma unroll 4
                    for (int ki = 0; ki < 16; ++ki) {
                        const int d  = sk + ki * 32 + lhi * 8;
                        const int d2 = d >> 1;
                        unsigned long long q0 = __hip_atomic_load(&hp64[d2+0], __ATOMIC_RELAXED, __HIP_MEMORY_SCOPE_AGENT);
                        unsigned long long q1 = __hip_atomic_load(&hp64[d2+1], __ATOMIC_RELAXED, __HIP_MEMORY_SCOPE_AGENT);
                        unsigned long long q2 = __hip_atomic_load(&hp64[d2+2], __ATOMIC_RELAXED, __HIP_MEMORY_SCOPE_AGENT);
                        unsigned long long q3 = __hip_atomic_load(&hp64[d2+3], __ATOMIC_RELAXED, __HIP_MEMORY_SCOPE_AGENT);
                        unsigned p[8] = {(unsigned)q0,(unsigned)(q0>>32),(unsigned)q1,(unsigned)(q1>>32),
                                         (unsigned)q2,(unsigned)(q2>>32),(unsigned)q3,(unsigned)(q3>>32)};
                        short8 ah, al; unpack8(p, ah, al);
                        const int kiG = (s - 2) * 16 + ki;
                        short8 uh = *(const short8*)&Wh[1][kiG*512 + lane*8];
                        short8 ul = *(const short8*)&Wl[1][kiG*512 + lane*8];
                        a0 = __builtin_amdgcn_mfma_f32_16x16x32_bf16(ah, uh, a0, 0, 0, 0);
                        a1 = __builtin_amdgcn_mfma_f32_16x16x32_bf16(al, uh, a1, 0, 0, 0);
                        a2 = __builtin_amdgcn_mfma_f32_16x16x32_bf16(ah, ul, a2, 0, 0, 0);
                    }
                }
            }

            f32x4 acc = a0 + a1 + a2;
            #pragma unroll
            for (int i = 0; i < 4; ++i)
                red[par][mt][s][lhi*4+i][ln15] = acc[i];
            __syncthreads();   // the only per-step intra-block barrier

            // ---- combine + state update + coherent publish + arrive (waves 0,1) ----
            if (tid < 128) {
                const int rmt = cb >> 4, rr = cb & 15;
                float z[4];
                #pragma unroll
                for (int g = 0; g < 4; ++g) {
                    const int n = g * 4 + cj;
                    z[g] = red[par][rmt][0][rr][n] + red[par][rmt][1][rr][n]
                         + red[par][rmt][2][rr][n] + red[par][rmt][3][rr][n] + bias[g];
                }
                float ig = hardsig(z[0]);
                float fg = hardsig(z[1]);
                float gg = tanhf(z[2]);
                float og = hardsig(z[3]);
                creg = fg * creg + ig * gg;
                float hval = og * tanhf(creg);
                short hi, lo; split2(hval, hi, lo);
                unsigned pv = ((unsigned)(unsigned short)hi << 16) | (unsigned)(unsigned short)lo;
                const size_t oidx = (size_t)cb * H_ + j0 + cj;
                if (layer == 0) {
                    __hip_atomic_store(&h1pk[(size_t)t * B_ * H_ + oidx], pv,
                                       __ATOMIC_RELAXED, __HIP_MEMORY_SCOPE_AGENT);
                } else {
                    __hip_atomic_store(&h2pk[(size_t)(t & 1) * B_ * H_ + oidx], pv,
                                       __ATOMIC_RELAXED, __HIP_MEMORY_SCOPE_AGENT);
                    if (t == T_ - 1) out[oidx] = hval;
                }
                // wave-level: all 64 lanes' stores ACKed at LLC before arriving
                asm volatile("s_waitcnt vmcnt(0)" ::: "memory");
                if (lane == 0) {
                    unsigned a = __hip_atomic_fetch_add(leafp, 1u, __ATOMIC_RELAXED, __HIP_MEMORY_SCOPE_AGENT);
                    if ((a & 31u) == 31u) {  // 2 waves x 16 blocks per leaf
                        unsigned r = __hip_atomic_fetch_add(rootp, 1u, __ATOMIC_RELAXED, __HIP_MEMORY_SCOPE_AGENT);
                        if ((r & 15u) == 15u) {
                            #pragma unroll
                            for (int i = 0; i < 16; ++i)
                                __hip_atomic_store(&bar[272 + i*16], (unsigned)(q + 1),
                                                   __ATOMIC_RELAXED, __HIP_MEMORY_SCOPE_AGENT);
                        }
                    }
                }
            }
        }
    }
}

extern "C" void kernel_launch(void* const* d_in, const int* in_sizes, int n_in,
                              void* d_out, int out_size, void* d_ws, size_t ws_size,
                              hipStream_t stream) {
    const float* x  = (const float*)d_in[0];
    const float* W0 = (const float*)d_in[1];
    const float* U0 = (const float*)d_in[2];
    const float* b0 = (const float*)d_in[3];
    const float* W1 = (const float*)d_in[4];
    const float* U1 = (const float*)d_in[5];
    const float* b1 = (const float*)d_in[6];
    float* out = (float*)d_out;

    char* ws = (char*)d_ws;
    const size_t off_h1 = 0;         // 64 MiB  packed h1 sequence
    const size_t off_h2 = 67108864;  // 256 KiB packed h2 double buffer
    const size_t off_zp = 67371008;  // 128 KiB zero page
    const size_t off_br = 67502080;  //   4 KiB barrier state

    unsigned* h1pk = (unsigned*)(ws + off_h1);
    unsigned* h2pk = (unsigned*)(ws + off_h2);
    unsigned* zp   = (unsigned*)(ws + off_zp);
    unsigned* bar  = (unsigned*)(ws + off_br);

    // reset zero page + barrier counters every launch (graph-capture safe)
    hipMemsetAsync(ws + off_zp, 0, 131072 + 4096, stream);

    hipLaunchKernelGGL(lstm_mfma2, dim3(NB), dim3(NT), 0, stream,
                       x, W0, U0, b0, W1, U1, b1,
                       h1pk, h2pk, zp, bar, out);
}